// Round 8
// baseline (80.137 us; speedup 1.0000x reference)
//
#include <hip/hip_runtime.h>
#include <math.h>

#define NS 256
#define EMB 120
#define NBLK 60
#define MODES 16
#define NPH 8

typedef float v2f __attribute__((ext_vector_type(2)));

__device__ __forceinline__ v2f cmul(v2f a, v2f b) {
    v2f axx = {a.x, a.x};
    v2f nyy = {-a.y, a.y};
    v2f byx = {b.y, b.x};
    return axx * b + nyy * byx;
}
__device__ __forceinline__ v2f cfma_conj(v2f a, v2f b, v2f c) {
    v2f axx = {a.x, a.x};
    v2f pyy = {a.y, -a.y};
    v2f byx = {b.y, b.x};
    return axx * b + (pyy * byx + c);
}

__device__ __forceinline__ float dpp_xor1(float x) {
    return __builtin_bit_cast(float,
        __builtin_amdgcn_mov_dpp(__builtin_bit_cast(int, x), 0xB1, 0xF, 0xF, true));
}
__device__ __forceinline__ float dpp_xor2(float x) {
    return __builtin_bit_cast(float,
        __builtin_amdgcn_mov_dpp(__builtin_bit_cast(int, x), 0x4E, 0xF, 0xF, true));
}

// Kernel A: x_emb = sigmoid(x@W.T+b); build V = U[:, :, 0:8] per sample.
__global__ __launch_bounds__(128) void emb_v_kernel(
    const float* __restrict__ x, const float* __restrict__ W,
    const float* __restrict__ bias, float* __restrict__ out_emb,
    float2* __restrict__ Vws)
{
    const int s = blockIdx.x;
    const int t = threadIdx.x;
    __shared__ float emb[EMB];
    __shared__ float ctA[NBLK], stA[NBLK], exA[NBLK], eyA[NBLK];

    if (t < EMB) {
        const float* xr = x + s * 64;
        const float* wr = W + t * 64;
        float acc = bias[t];
        #pragma unroll
        for (int k = 0; k < 64; ++k) acc = fmaf(xr[k], wr[k], acc);
        float e = 1.0f / (1.0f + expf(-acc));
        emb[t] = e;
        out_emb[s * EMB + t] = e;
    }
    __syncthreads();

    if (t < NBLK) {
        float th = emb[2 * t]     * 1.57079632679489662f;
        float ph = emb[2 * t + 1] * 6.28318530717958648f;
        float st, ct, sp, cp;
        sincosf(th, &st, &ct);
        sincosf(ph, &sp, &cp);
        ctA[t] = ct; stA[t] = st; exA[t] = cp; eyA[t] = sp;
    }
    __syncthreads();

    if (t < NPH) {
        const int c = t;
        float2 u[MODES];
        #pragma unroll
        for (int m = 0; m < MODES; ++m) {
            u[m].x = (m == c) ? 1.0f : 0.0f;
            u[m].y = 0.0f;
        }
        int bi = 0;
        #pragma unroll
        for (int d = 0; d < 8; ++d) {
            const int off = d & 1;
            const int nb = 8 - off;
            #pragma unroll
            for (int k = 0; k < nb; ++k) {
                float ct = ctA[bi], st = stA[bi], ex = exA[bi], ey = eyA[bi];
                ++bi;
                const int r0 = off + 2 * k;
                float2 u0 = u[r0], u1 = u[r0 + 1];
                float2 n0, n1;
                n0.x = ex * ct * u0.x - ey * ct * u0.y - st * u1.x;
                n0.y = ex * ct * u0.y + ey * ct * u0.x - st * u1.y;
                n1.x = ex * st * u0.x - ey * st * u0.y + ct * u1.x;
                n1.y = ex * st * u0.y + ey * st * u0.x + ct * u1.y;
                u[r0] = n0; u[r0 + 1] = n1;
            }
        }
        #pragma unroll
        for (int m = 0; m < MODES; ++m)
            Vws[(s * MODES + m) * NPH + c] = u[m];
    }
}

// Kernel B: upper-triangular 8x8 pair tiles, 4 threads/pair, DPP cross-lane.
// Glynn phase is a LOOP (8 trips x 8 terms, ~1.4 KB body) instead of a fully
// unrolled ~10 KB straight-line region — tests the I-fetch-streaming theory.
__global__ __launch_bounds__(256, 2) void perm_kernel(
    const float2* __restrict__ Vws, float* __restrict__ outK)
{
    __shared__ float2 sva[8][132];
    __shared__ float2 svb[8][132];

    const int L = blockIdx.x;
    int t = (int)((65.0f - sqrtf(4225.0f - 8.0f * (float)L)) * 0.5f);
    while (t * (65 - t) / 2 > L) --t;
    while ((t + 1) * (65 - (t + 1)) / 2 <= L) ++t;
    const int ta = t;
    const int tb = ta + (L - t * (65 - t) / 2);

    const int tid = threadIdx.x;
    const float4* srcA = (const float4*)(Vws + (size_t)ta * 8 * 128);
    const float4* srcB = (const float4*)(Vws + (size_t)tb * 8 * 128);
    #pragma unroll
    for (int r = 0; r < 2; ++r) {
        int idx = r * 256 + tid;
        int row = idx >> 6;
        int c4  = idx & 63;
        *(float4*)&sva[row][c4 * 2] = srcA[idx];
        *(float4*)&svb[row][c4 * 2] = srcB[idx];
    }
    __syncthreads();

    const int p   = tid >> 2;
    const int sub = tid & 3;
    const int h   = sub & 1;
    const int e   = sub >> 1;
    const int pa  = p >> 3;
    const int pb  = p & 7;

    // ---- build own 2 rows: rows 4h+2e, 4h+2e+1 of G = Va^H Vb ----
    v2f Go[2][8];
    #pragma unroll
    for (int i = 0; i < 2; ++i)
        #pragma unroll
        for (int j = 0; j < 8; ++j) Go[i][j] = (v2f){0.f, 0.f};

    #pragma unroll 2
    for (int m = 0; m < 16; ++m) {
        float4 va4 = *(const float4*)&sva[pa][m * 8 + 4 * h + 2 * e];
        v2f a0 = {va4.x, va4.y};
        v2f a1 = {va4.z, va4.w};
        v2f vb[8];
        #pragma unroll
        for (int jj = 0; jj < 4; ++jj) {
            float4 b4 = *(const float4*)&svb[pb][m * 8 + 2 * jj];
            vb[2 * jj]     = (v2f){b4.x, b4.y};
            vb[2 * jj + 1] = (v2f){b4.z, b4.w};
        }
        #pragma unroll
        for (int j = 0; j < 8; ++j) {
            Go[0][j] = cfma_conj(a0, vb[j], Go[0][j]);
            Go[1][j] = cfma_conj(a1, vb[j], Go[1][j]);
        }
    }

    // ---- exchange 2 rows with delta-partner (xor 2) via DPP ----
    v2f Gp[2][8];
    #pragma unroll
    for (int i = 0; i < 2; ++i)
        #pragma unroll
        for (int j = 0; j < 8; ++j) {
            Gp[i][j].x = dpp_xor2(Go[i][j].x);
            Gp[i][j].y = dpp_xor2(Go[i][j].y);
        }

    // ---- rs init: delta = (+1,...,+1, sgn_e) ----
    const float sgn = 1.0f - 2.0f * (float)e;
    const v2f sgnv = {sgn, sgn};
    v2f rs[4];
    #pragma unroll
    for (int r = 0; r < 2; ++r) {
        {
            v2f s = ((Go[r][0] + Go[r][1]) + (Go[r][2] + Go[r][3]))
                  + ((Go[r][4] + Go[r][5]) + Go[r][6]);
            rs[r] = sgnv * Go[r][7] + s;
        }
        {
            v2f s = ((Gp[r][0] + Gp[r][1]) + (Gp[r][2] + Gp[r][3]))
                  + ((Gp[r][4] + Gp[r][5]) + Gp[r][6]);
            rs[2 + r] = sgnv * Gp[r][7] + s;
        }
    }

    v2f acc;

#define TREE(OUT) do {                                                \
        v2f t01 = cmul(rs[0], rs[1]);                                 \
        v2f t23 = cmul(rs[2], rs[3]);                                 \
        v2f half = cmul(t01, t23);                                    \
        v2f oth;                                                      \
        oth.x = dpp_xor1(half.x);                                     \
        oth.y = dpp_xor1(half.y);                                     \
        OUT = cmul(half, oth);                                        \
    } while (0)

#define UPD(J, S) do {                                                \
        const v2f sv = {(S), (S)};                                    \
        rs[0] = sv * Go[0][J] + rs[0];                                \
        rs[1] = sv * Go[1][J] + rs[1];                                \
        rs[2] = sv * Gp[0][J] + rs[2];                                \
        rs[3] = sv * Gp[1][J] + rs[3];                                \
    } while (0)

#define TERM(TS) do {                                                 \
        v2f fullp; TREE(fullp);                                       \
        const v2f tv = {(TS), (TS)};                                  \
        acc = tv * fullp + acc;                                       \
    } while (0)

    TREE(acc);   // t=0, sign +

    // 8 trips x 8 terms. Terms 8o+1..8o+7 have static cols/signs; term 8(o+1)
    // toggles col c = 4+ctz(o+1) in {4,5,6} with sign s8 — wave-uniform,
    // applied via cndmask-selected column (no dynamic register indexing).
    #pragma unroll 1
    for (int o = 0; o < 8; ++o) {
        const float s4 = (o & 1) ? 2.f : -2.f;
        UPD(1, -2.f); TERM(-1.f);           // t=8o+1
        UPD(2, -2.f); TERM( 1.f);           // t=8o+2
        UPD(1,  2.f); TERM(-1.f);           // t=8o+3
        UPD(3,  s4 ); TERM( 1.f);           // t=8o+4
        UPD(1, -2.f); TERM(-1.f);           // t=8o+5
        UPD(2,  2.f); TERM( 1.f);           // t=8o+6
        UPD(1,  2.f); TERM(-1.f);           // t=8o+7
        if (o < 7) {                        // t=8(o+1)
            const int qq = o + 1;
            const int cz = __builtin_ctz(qq);          // 0..2 -> col 4..6
            const float s8 = ((qq >> (cz + 1)) & 1) ? 2.f : -2.f;
            const bool is4 = (cz == 0);
            const bool is5 = (cz == 1);
            const v2f s8v = {s8, s8};
            #pragma unroll
            for (int r = 0; r < 2; ++r) {
                v2f co = is4 ? Go[r][4] : (is5 ? Go[r][5] : Go[r][6]);
                v2f cp = is4 ? Gp[r][4] : (is5 ? Gp[r][5] : Gp[r][6]);
                rs[r]     = s8v * co + rs[r];
                rs[2 + r] = s8v * cp + rs[2 + r];
            }
            TERM(1.f);
        }
    }
#undef UPD
#undef TERM
#undef TREE

    float ax = sgn * acc.x, ay = sgn * acc.y;
    ax += dpp_xor2(ax);
    ay += dpp_xor2(ay);

    if (sub == 0) {
        const int a = ta * 8 + pa;
        const int b = tb * 8 + pb;
        float K = fmaf(ax, ax, ay * ay) * (1.0f / 16384.0f);
        if (a == b) K = 1.0f;
        outK[a * 256 + b] = K;
        outK[b * 256 + a] = K;
    }
}

extern "C" void kernel_launch(void* const* d_in, const int* in_sizes, int n_in,
                              void* d_out, int out_size, void* d_ws, size_t ws_size,
                              hipStream_t stream) {
    const float* x    = (const float*)d_in[0];
    const float* W    = (const float*)d_in[1];
    const float* bias = (const float*)d_in[2];
    float* out     = (float*)d_out;
    float* out_emb = out;              // 256*120
    float* outK    = out + NS * EMB;   // 256*256
    float2* Vws    = (float2*)d_ws;    // 256 KB

    emb_v_kernel<<<NS, 128, 0, stream>>>(x, W, bias, out_emb, Vws);
    perm_kernel<<<528, 256, 0, stream>>>(Vws, outK);
}

// Round 9
// 79.711 us; speedup vs baseline: 1.0053x; 1.0053x over previous
//
#include <hip/hip_runtime.h>
#include <math.h>

#define NS 256
#define EMB 120
#define NBLK 60
#define MODES 16
#define NPH 8

// scalar complex mul: 4 inst (mul, fma, mul, fma)
#define CMUL(r, a, b) do {                         \
        (r).x = fmaf((a).x, (b).x, -((a).y * (b).y)); \
        (r).y = fmaf((a).x, (b).y,  ((a).y * (b).x)); \
    } while (0)

__device__ __forceinline__ float dpp_xor1(float x) {
    return __builtin_bit_cast(float,
        __builtin_amdgcn_mov_dpp(__builtin_bit_cast(int, x), 0xB1, 0xF, 0xF, true));
}
__device__ __forceinline__ float dpp_xor2(float x) {
    return __builtin_bit_cast(float,
        __builtin_amdgcn_mov_dpp(__builtin_bit_cast(int, x), 0x4E, 0xF, 0xF, true));
}

// Kernel A: x_emb = sigmoid(x@W.T+b); build V = U[:, :, 0:8] per sample.
__global__ __launch_bounds__(128) void emb_v_kernel(
    const float* __restrict__ x, const float* __restrict__ W,
    const float* __restrict__ bias, float* __restrict__ out_emb,
    float2* __restrict__ Vws)
{
    const int s = blockIdx.x;
    const int t = threadIdx.x;
    __shared__ float emb[EMB];
    __shared__ float ctA[NBLK], stA[NBLK], exA[NBLK], eyA[NBLK];

    if (t < EMB) {
        const float* xr = x + s * 64;
        const float* wr = W + t * 64;
        float acc = bias[t];
        #pragma unroll
        for (int k = 0; k < 64; ++k) acc = fmaf(xr[k], wr[k], acc);
        float e = 1.0f / (1.0f + expf(-acc));
        emb[t] = e;
        out_emb[s * EMB + t] = e;
    }
    __syncthreads();

    if (t < NBLK) {
        float th = emb[2 * t]     * 1.57079632679489662f;
        float ph = emb[2 * t + 1] * 6.28318530717958648f;
        float st, ct, sp, cp;
        sincosf(th, &st, &ct);
        sincosf(ph, &sp, &cp);
        ctA[t] = ct; stA[t] = st; exA[t] = cp; eyA[t] = sp;
    }
    __syncthreads();

    if (t < NPH) {
        const int c = t;
        float2 u[MODES];
        #pragma unroll
        for (int m = 0; m < MODES; ++m) {
            u[m].x = (m == c) ? 1.0f : 0.0f;
            u[m].y = 0.0f;
        }
        int bi = 0;
        #pragma unroll
        for (int d = 0; d < 8; ++d) {
            const int off = d & 1;
            const int nb = 8 - off;
            #pragma unroll
            for (int k = 0; k < nb; ++k) {
                float ct = ctA[bi], st = stA[bi], ex = exA[bi], ey = eyA[bi];
                ++bi;
                const int r0 = off + 2 * k;
                float2 u0 = u[r0], u1 = u[r0 + 1];
                float2 n0, n1;
                n0.x = ex * ct * u0.x - ey * ct * u0.y - st * u1.x;
                n0.y = ex * ct * u0.y + ey * ct * u0.x - st * u1.y;
                n1.x = ex * st * u0.x - ey * st * u0.y + ct * u1.x;
                n1.y = ex * st * u0.y + ey * st * u0.x + ct * u1.y;
                u[r0] = n0; u[r0 + 1] = n1;
            }
        }
        #pragma unroll
        for (int m = 0; m < MODES; ++m)
            Vws[(s * MODES + m) * NPH + c] = u[m];
    }
}

// Kernel B: 512-thread block = 8x8 upper-triangular pair tile, 8 lanes/pair.
// Lane sub s: h = s&1 (row half: rows 4h..4h+3), d = s>>1 (fixes delta5,delta6).
// G-build distributed: each lane computes ONE row of G = Va^H Vb (128 cmul,
// the 1024-cmul/pair minimum / 8), exchanged via LDS. Glynn: Gray over
// delta1..delta4,delta7 = 32 terms/lane (static cols/coeffs, straight-line).
// Cross-half product: quad_perm xor1. delta-sum: quad_perm xor2 + shfl_xor(4).
__global__ __launch_bounds__(512, 4) void perm_kernel(
    const float2* __restrict__ Vws, float* __restrict__ outK)
{
    __shared__ float2 sG[64][66];                       // 33792 B (overlay)
    float2 (*sva)[132] = (float2(*)[132])sG;            // first 8448 B
    float2 (*svb)[132] = (float2(*)[132])((char*)sG + 8448);

    // triangular decode: blockIdx -> (ta, tb), ta <= tb (32x33/2 = 528 blocks)
    const int L = blockIdx.x;
    int t = (int)((65.0f - sqrtf(4225.0f - 8.0f * (float)L)) * 0.5f);
    while (t * (65 - t) / 2 > L) --t;
    while ((t + 1) * (65 - (t + 1)) / 2 <= L) ++t;
    const int ta = t;
    const int tb = ta + (L - t * (65 - t) / 2);

    const int tid = threadIdx.x;   // 0..511
    // stage both tiles: 512 float4 each side, 1 A-load + 1 B-load per thread
    const float4* srcA = (const float4*)(Vws + (size_t)ta * 8 * 128);
    const float4* srcB = (const float4*)(Vws + (size_t)tb * 8 * 128);
    {
        const int row = tid >> 6;
        const int c4  = tid & 63;
        float4 fa = srcA[tid];
        float4 fb = srcB[tid];
        *(float4*)&sva[row][c4 * 2] = fa;
        *(float4*)&svb[row][c4 * 2] = fb;
    }
    __syncthreads();

    const int p  = tid >> 3;    // pair 0..63
    const int s  = tid & 7;     // sub-lane
    const int h  = s & 1;       // row half
    const int d  = s >> 1;      // 2 bits: delta5 = bit0, delta6 = bit1
    const int pa = p >> 3;
    const int pb = p & 7;

    // ---- G-build: own row i = s:  G[s][j] = sum_m conj(Va[m][s]) Vb[m][j] ----
    float2 Gb[8];
    #pragma unroll
    for (int j = 0; j < 8; ++j) { Gb[j].x = 0.f; Gb[j].y = 0.f; }

    #pragma unroll 4
    for (int m = 0; m < 16; ++m) {
        float2 va = sva[pa][m * 8 + s];
        float2 vb[8];
        #pragma unroll
        for (int jj = 0; jj < 4; ++jj) {
            float4 b4 = *(const float4*)&svb[pb][m * 8 + 2 * jj];
            vb[2 * jj].x     = b4.x; vb[2 * jj].y     = b4.y;
            vb[2 * jj + 1].x = b4.z; vb[2 * jj + 1].y = b4.w;
        }
        #pragma unroll
        for (int j = 0; j < 8; ++j) {
            Gb[j].x = fmaf(va.x, vb[j].x, fmaf(va.y, vb[j].y, Gb[j].x));
            Gb[j].y = fmaf(va.x, vb[j].y, fmaf(-va.y, vb[j].x, Gb[j].y));
        }
    }
    __syncthreads();   // all sva/svb reads done before sG overwrite

    // write own row to sG, then read rows 4h..4h+3
    #pragma unroll
    for (int jj = 0; jj < 4; ++jj) {
        float4 w;
        w.x = Gb[2 * jj].x;     w.y = Gb[2 * jj].y;
        w.z = Gb[2 * jj + 1].x; w.w = Gb[2 * jj + 1].y;
        *(float4*)&sG[p][s * 8 + 2 * jj] = w;
    }
    __syncthreads();

    float2 G[4][8];
    #pragma unroll
    for (int k = 0; k < 4; ++k)
        #pragma unroll
        for (int jj = 0; jj < 4; ++jj) {
            float4 g4 = *(const float4*)&sG[p][(4 * h + k) * 8 + 2 * jj];
            G[k][2 * jj].x     = g4.x; G[k][2 * jj].y     = g4.y;
            G[k][2 * jj + 1].x = g4.z; G[k][2 * jj + 1].y = g4.w;
        }

    // ---- rs init: delta = +1 except delta5 = s5, delta6 = s6 ----
    const float s5 = (d & 1) ? -1.f : 1.f;
    const float s6 = (d & 2) ? -1.f : 1.f;
    float2 rs[4];
    #pragma unroll
    for (int i = 0; i < 4; ++i) {
        float sx = ((G[i][0].x + G[i][1].x) + (G[i][2].x + G[i][3].x))
                 + (G[i][4].x + G[i][7].x);
        float sy = ((G[i][0].y + G[i][1].y) + (G[i][2].y + G[i][3].y))
                 + (G[i][4].y + G[i][7].y);
        sx = fmaf(s5, G[i][5].x, sx); sx = fmaf(s6, G[i][6].x, sx);
        sy = fmaf(s5, G[i][5].y, sy); sy = fmaf(s6, G[i][6].y, sy);
        rs[i].x = sx; rs[i].y = sy;
    }

    float2 acc;

#define TREE(OUTX, OUTY) do {                                         \
        float2 m01, m23, hf, fl;                                      \
        CMUL(m01, rs[0], rs[1]);                                      \
        CMUL(m23, rs[2], rs[3]);                                      \
        CMUL(hf, m01, m23);                                           \
        float2 ot;                                                    \
        ot.x = dpp_xor1(hf.x);                                        \
        ot.y = dpp_xor1(hf.y);                                        \
        CMUL(fl, hf, ot);                                             \
        OUTX = fl.x; OUTY = fl.y;                                     \
    } while (0)

#define UPD(J, C) do {                                                \
        _Pragma("unroll")                                             \
        for (int i = 0; i < 4; ++i) {                                 \
            rs[i].x = fmaf((C), G[i][J].x, rs[i].x);                  \
            rs[i].y = fmaf((C), G[i][J].y, rs[i].y);                  \
        }                                                             \
    } while (0)

#define TERM(TS) do {                                                 \
        float fx, fy; TREE(fx, fy);                                   \
        acc.x = fmaf((TS), fx, acc.x);                                \
        acc.y = fmaf((TS), fy, acc.y);                                \
    } while (0)

    TREE(acc.x, acc.y);                     // t=0, sign +
    // Gray over (delta1..delta4, delta7); cols: bit0..3 -> 1..4, bit4 -> 7
    UPD(1, -2.f); TERM(-1.f);               // t=1
    UPD(2, -2.f); TERM( 1.f);               // t=2
    UPD(1,  2.f); TERM(-1.f);               // t=3
    UPD(3, -2.f); TERM( 1.f);               // t=4
    UPD(1, -2.f); TERM(-1.f);               // t=5
    UPD(2,  2.f); TERM( 1.f);               // t=6
    UPD(1,  2.f); TERM(-1.f);               // t=7
    UPD(4, -2.f); TERM( 1.f);               // t=8
    UPD(1, -2.f); TERM(-1.f);               // t=9
    UPD(2, -2.f); TERM( 1.f);               // t=10
    UPD(1,  2.f); TERM(-1.f);               // t=11
    UPD(3,  2.f); TERM( 1.f);               // t=12
    UPD(1, -2.f); TERM(-1.f);               // t=13
    UPD(2,  2.f); TERM( 1.f);               // t=14
    UPD(1,  2.f); TERM(-1.f);               // t=15
    UPD(7, -2.f); TERM( 1.f);               // t=16
    UPD(1, -2.f); TERM(-1.f);               // t=17
    UPD(2, -2.f); TERM( 1.f);               // t=18
    UPD(1,  2.f); TERM(-1.f);               // t=19
    UPD(3, -2.f); TERM( 1.f);               // t=20
    UPD(1, -2.f); TERM(-1.f);               // t=21
    UPD(2,  2.f); TERM( 1.f);               // t=22
    UPD(1,  2.f); TERM(-1.f);               // t=23
    UPD(4,  2.f); TERM( 1.f);               // t=24
    UPD(1, -2.f); TERM(-1.f);               // t=25
    UPD(2, -2.f); TERM( 1.f);               // t=26
    UPD(1,  2.f); TERM(-1.f);               // t=27
    UPD(3,  2.f); TERM( 1.f);               // t=28
    UPD(1, -2.f); TERM(-1.f);               // t=29
    UPD(2,  2.f); TERM( 1.f);               // t=30
    UPD(1,  2.f); TERM(-1.f);               // t=31
#undef UPD
#undef TERM
#undef TREE

    // fold fixed-delta sign; sum over d (lane bits 1,2): xor2 (DPP) + xor4 (shfl)
    const float sq = s5 * s6;
    float ax = sq * acc.x, ay = sq * acc.y;
    ax += dpp_xor2(ax);
    ay += dpp_xor2(ay);
    ax += __shfl_xor(ax, 4);
    ay += __shfl_xor(ay, 4);

    if (s == 0) {
        const int a = ta * 8 + pa;
        const int b = tb * 8 + pb;
        float K = fmaf(ax, ax, ay * ay) * (1.0f / 16384.0f);
        if (a == b) K = 1.0f;
        outK[a * 256 + b] = K;
        outK[b * 256 + a] = K;   // Hermitian symmetry
    }
}

extern "C" void kernel_launch(void* const* d_in, const int* in_sizes, int n_in,
                              void* d_out, int out_size, void* d_ws, size_t ws_size,
                              hipStream_t stream) {
    const float* x    = (const float*)d_in[0];
    const float* W    = (const float*)d_in[1];
    const float* bias = (const float*)d_in[2];
    float* out     = (float*)d_out;
    float* out_emb = out;              // 256*120
    float* outK    = out + NS * EMB;   // 256*256
    float2* Vws    = (float2*)d_ws;    // 256 KB

    emb_v_kernel<<<NS, 128, 0, stream>>>(x, W, bias, out_emb, Vws);
    perm_kernel<<<528, 512, 0, stream>>>(Vws, outK);
}

// Round 10
// 76.571 us; speedup vs baseline: 1.0466x; 1.0410x over previous
//
#include <hip/hip_runtime.h>
#include <math.h>

#define NS 256
#define EMB 120
#define NBLK 60
#define MODES 16
#define NPH 8

typedef float v2f __attribute__((ext_vector_type(2)));

__device__ __forceinline__ v2f cmul(v2f a, v2f b) {
    v2f axx = {a.x, a.x};
    v2f nyy = {-a.y, a.y};
    v2f byx = {b.y, b.x};
    return axx * b + nyy * byx;
}
__device__ __forceinline__ v2f cfma_conj(v2f a, v2f b, v2f c) {
    v2f axx = {a.x, a.x};
    v2f pyy = {a.y, -a.y};
    v2f byx = {b.y, b.x};
    return axx * b + (pyy * byx + c);
}

__device__ __forceinline__ float dpp_xor1(float x) {
    return __builtin_bit_cast(float,
        __builtin_amdgcn_mov_dpp(__builtin_bit_cast(int, x), 0xB1, 0xF, 0xF, true));
}
__device__ __forceinline__ float dpp_xor2(float x) {
    return __builtin_bit_cast(float,
        __builtin_amdgcn_mov_dpp(__builtin_bit_cast(int, x), 0x4E, 0xF, 0xF, true));
}

// Kernel A: x_emb = sigmoid(x@W.T+b); build V = U[:, :, 0:8] per sample.
__global__ __launch_bounds__(128) void emb_v_kernel(
    const float* __restrict__ x, const float* __restrict__ W,
    const float* __restrict__ bias, float* __restrict__ out_emb,
    float2* __restrict__ Vws)
{
    const int s = blockIdx.x;
    const int t = threadIdx.x;
    __shared__ float emb[EMB];
    __shared__ float ctA[NBLK], stA[NBLK], exA[NBLK], eyA[NBLK];

    if (t < EMB) {
        const float* xr = x + s * 64;
        const float* wr = W + t * 64;
        float acc = bias[t];
        #pragma unroll
        for (int k = 0; k < 64; ++k) acc = fmaf(xr[k], wr[k], acc);
        float e = 1.0f / (1.0f + expf(-acc));
        emb[t] = e;
        out_emb[s * EMB + t] = e;
    }
    __syncthreads();

    if (t < NBLK) {
        float th = emb[2 * t]     * 1.57079632679489662f;
        float ph = emb[2 * t + 1] * 6.28318530717958648f;
        float st, ct, sp, cp;
        sincosf(th, &st, &ct);
        sincosf(ph, &sp, &cp);
        ctA[t] = ct; stA[t] = st; exA[t] = cp; eyA[t] = sp;
    }
    __syncthreads();

    if (t < NPH) {
        const int c = t;
        float2 u[MODES];
        #pragma unroll
        for (int m = 0; m < MODES; ++m) {
            u[m].x = (m == c) ? 1.0f : 0.0f;
            u[m].y = 0.0f;
        }
        int bi = 0;
        #pragma unroll
        for (int d = 0; d < 8; ++d) {
            const int off = d & 1;
            const int nb = 8 - off;
            #pragma unroll
            for (int k = 0; k < nb; ++k) {
                float ct = ctA[bi], st = stA[bi], ex = exA[bi], ey = eyA[bi];
                ++bi;
                const int r0 = off + 2 * k;
                float2 u0 = u[r0], u1 = u[r0 + 1];
                float2 n0, n1;
                n0.x = ex * ct * u0.x - ey * ct * u0.y - st * u1.x;
                n0.y = ex * ct * u0.y + ey * ct * u0.x - st * u1.y;
                n1.x = ex * st * u0.x - ey * st * u0.y + ct * u1.x;
                n1.y = ex * st * u0.y + ey * st * u0.x + ct * u1.y;
                u[r0] = n0; u[r0 + 1] = n1;
            }
        }
        #pragma unroll
        for (int m = 0; m < MODES; ++m)
            Vws[(s * MODES + m) * NPH + c] = u[m];
    }
}

// Kernel B (R7 base + dual-chain ILP): upper-triangular 8x8 pair tiles,
// 4 threads/pair = (row-half h) x (delta7-half e). Each thread runs TWO
// independent Glynn Gray chains (delta6 = +1 and -1) over delta1..delta5,
// interleaved so chain B's UPDs overlap chain A's dependent product tree.
__global__ __launch_bounds__(256, 2) void perm_kernel(
    const float2* __restrict__ Vws, float* __restrict__ outK)
{
    __shared__ float2 sva[8][132];
    __shared__ float2 svb[8][132];

    const int L = blockIdx.x;
    int t = (int)((65.0f - sqrtf(4225.0f - 8.0f * (float)L)) * 0.5f);
    while (t * (65 - t) / 2 > L) --t;
    while ((t + 1) * (65 - (t + 1)) / 2 <= L) ++t;
    const int ta = t;
    const int tb = ta + (L - t * (65 - t) / 2);

    const int tid = threadIdx.x;
    const float4* srcA = (const float4*)(Vws + (size_t)ta * 8 * 128);
    const float4* srcB = (const float4*)(Vws + (size_t)tb * 8 * 128);
    #pragma unroll
    for (int r = 0; r < 2; ++r) {
        int idx = r * 256 + tid;
        int row = idx >> 6;
        int c4  = idx & 63;
        *(float4*)&sva[row][c4 * 2] = srcA[idx];
        *(float4*)&svb[row][c4 * 2] = srcB[idx];
    }
    __syncthreads();

    const int p   = tid >> 2;
    const int sub = tid & 3;
    const int h   = sub & 1;
    const int e   = sub >> 1;
    const int pa  = p >> 3;
    const int pb  = p & 7;

    // ---- build own 2 rows: rows 4h+2e, 4h+2e+1 of G = Va^H Vb ----
    v2f Go[2][8];
    #pragma unroll
    for (int i = 0; i < 2; ++i)
        #pragma unroll
        for (int j = 0; j < 8; ++j) Go[i][j] = (v2f){0.f, 0.f};

    #pragma unroll 2
    for (int m = 0; m < 16; ++m) {
        float4 va4 = *(const float4*)&sva[pa][m * 8 + 4 * h + 2 * e];
        v2f a0 = {va4.x, va4.y};
        v2f a1 = {va4.z, va4.w};
        v2f vb[8];
        #pragma unroll
        for (int jj = 0; jj < 4; ++jj) {
            float4 b4 = *(const float4*)&svb[pb][m * 8 + 2 * jj];
            vb[2 * jj]     = (v2f){b4.x, b4.y};
            vb[2 * jj + 1] = (v2f){b4.z, b4.w};
        }
        #pragma unroll
        for (int j = 0; j < 8; ++j) {
            Go[0][j] = cfma_conj(a0, vb[j], Go[0][j]);
            Go[1][j] = cfma_conj(a1, vb[j], Go[1][j]);
        }
    }

    // ---- exchange 2 rows with delta-partner (xor 2) via DPP ----
    v2f Gp[2][8];
    #pragma unroll
    for (int i = 0; i < 2; ++i)
        #pragma unroll
        for (int j = 0; j < 8; ++j) {
            Gp[i][j].x = dpp_xor2(Go[i][j].x);
            Gp[i][j].y = dpp_xor2(Go[i][j].y);
        }

    // ---- chain inits ----
    // A: delta = (+...+, d6=+1, d7=sgn_e) ; B: same with d6=-1
    const float sgn = 1.0f - 2.0f * (float)e;
    const v2f sgnv = {sgn, sgn};
    const v2f m2   = {-2.f, -2.f};
    v2f rsa[4], rsb[4];
    #pragma unroll
    for (int r = 0; r < 2; ++r) {
        {
            v2f s = ((Go[r][0] + Go[r][1]) + (Go[r][2] + Go[r][3]))
                  + ((Go[r][4] + Go[r][5]) + Go[r][6]);
            rsa[r] = sgnv * Go[r][7] + s;
            rsb[r] = m2 * Go[r][6] + rsa[r];
        }
        {
            v2f s = ((Gp[r][0] + Gp[r][1]) + (Gp[r][2] + Gp[r][3]))
                  + ((Gp[r][4] + Gp[r][5]) + Gp[r][6]);
            rsa[2 + r] = sgnv * Gp[r][7] + s;
            rsb[2 + r] = m2 * Gp[r][6] + rsa[2 + r];
        }
    }

    v2f acc;

#define TREEQ(RS, OUT) do {                                           \
        v2f t01 = cmul((RS)[0], (RS)[1]);                             \
        v2f t23 = cmul((RS)[2], (RS)[3]);                             \
        v2f half = cmul(t01, t23);                                    \
        v2f oth;                                                      \
        oth.x = dpp_xor1(half.x);                                     \
        oth.y = dpp_xor1(half.y);                                     \
        OUT = cmul(half, oth);                                        \
    } while (0)

#define UPD2(J, S) do {                                               \
        const v2f sv = {(S), (S)};                                    \
        rsa[0] = sv * Go[0][J] + rsa[0];                              \
        rsa[1] = sv * Go[1][J] + rsa[1];                              \
        rsa[2] = sv * Gp[0][J] + rsa[2];                              \
        rsa[3] = sv * Gp[1][J] + rsa[3];                              \
        rsb[0] = sv * Go[0][J] + rsb[0];                              \
        rsb[1] = sv * Go[1][J] + rsb[1];                              \
        rsb[2] = sv * Gp[0][J] + rsb[2];                              \
        rsb[3] = sv * Gp[1][J] + rsb[3];                              \
    } while (0)

// acc += TS*treeA - TS*treeB   (chain B carries global delta6=-1 factor)
#define STEP(J, S, TS) do {                                           \
        UPD2(J, S);                                                   \
        v2f fa, fb;                                                   \
        TREEQ(rsa, fa);                                               \
        TREEQ(rsb, fb);                                               \
        const v2f tv = {(TS), (TS)};                                  \
        acc = tv * fa + acc;                                          \
        acc = (-tv) * fb + acc;                                       \
    } while (0)

    {   // t=0: acc = treeA - treeB
        v2f fa, fb;
        TREEQ(rsa, fa);
        TREEQ(rsb, fb);
        acc = fa - fb;
    }
    STEP(1, -2.f, -1.f);    // t=1
    STEP(2, -2.f,  1.f);    // t=2
    STEP(1,  2.f, -1.f);    // t=3
    STEP(3, -2.f,  1.f);    // t=4
    STEP(1, -2.f, -1.f);    // t=5
    STEP(2,  2.f,  1.f);    // t=6
    STEP(1,  2.f, -1.f);    // t=7
    STEP(4, -2.f,  1.f);    // t=8
    STEP(1, -2.f, -1.f);    // t=9
    STEP(2, -2.f,  1.f);    // t=10
    STEP(1,  2.f, -1.f);    // t=11
    STEP(3,  2.f,  1.f);    // t=12
    STEP(1, -2.f, -1.f);    // t=13
    STEP(2,  2.f,  1.f);    // t=14
    STEP(1,  2.f, -1.f);    // t=15
    STEP(5, -2.f,  1.f);    // t=16
    STEP(1, -2.f, -1.f);    // t=17
    STEP(2, -2.f,  1.f);    // t=18
    STEP(1,  2.f, -1.f);    // t=19
    STEP(3, -2.f,  1.f);    // t=20
    STEP(1, -2.f, -1.f);    // t=21
    STEP(2,  2.f,  1.f);    // t=22
    STEP(1,  2.f, -1.f);    // t=23
    STEP(4,  2.f,  1.f);    // t=24
    STEP(1, -2.f, -1.f);    // t=25
    STEP(2, -2.f,  1.f);    // t=26
    STEP(1,  2.f, -1.f);    // t=27
    STEP(3,  2.f,  1.f);    // t=28
    STEP(1, -2.f, -1.f);    // t=29
    STEP(2,  2.f,  1.f);    // t=30
    STEP(1,  2.f, -1.f);    // t=31
#undef STEP
#undef UPD2
#undef TREEQ

    // fold delta7 sign, combine the two delta7-halves (xor 2, DPP)
    float ax = sgn * acc.x, ay = sgn * acc.y;
    ax += dpp_xor2(ax);
    ay += dpp_xor2(ay);

    if (sub == 0) {
        const int a = ta * 8 + pa;
        const int b = tb * 8 + pb;
        float K = fmaf(ax, ax, ay * ay) * (1.0f / 16384.0f);
        if (a == b) K = 1.0f;
        outK[a * 256 + b] = K;
        outK[b * 256 + a] = K;
    }
}

extern "C" void kernel_launch(void* const* d_in, const int* in_sizes, int n_in,
                              void* d_out, int out_size, void* d_ws, size_t ws_size,
                              hipStream_t stream) {
    const float* x    = (const float*)d_in[0];
    const float* W    = (const float*)d_in[1];
    const float* bias = (const float*)d_in[2];
    float* out     = (float*)d_out;
    float* out_emb = out;              // 256*120
    float* outK    = out + NS * EMB;   // 256*256
    float2* Vws    = (float2*)d_ws;    // 256 KB

    emb_v_kernel<<<NS, 128, 0, stream>>>(x, W, bias, out_emb, Vws);
    perm_kernel<<<528, 256, 0, stream>>>(Vws, outK);
}